// Round 6
// baseline (180.605 us; speedup 1.0000x reference)
//
#include <hip/hip_runtime.h>

typedef __attribute__((ext_vector_type(8))) short bf16x8;
typedef __attribute__((ext_vector_type(4))) float f32x4;

#define E_DIM 100
#define L_SEQ 20
#define NV    30000
#define NVP   30080
#define MROWS 2000
#define MPAD  2048
#define KP    128

__device__ inline float sigmoidf_(float x){ return 1.f/(1.f+expf(-x)); }
__device__ inline unsigned short f2bf(float f){
  unsigned int u = __float_as_uint(f);
  return (unsigned short)((u + 0x7fffu + ((u>>16)&1u)) >> 16);
}
__device__ inline float dot4(float4 a, float4 b){
  return a.x*b.x + a.y*b.y + a.z*b.z + a.w*b.w;
}

// ================= PREP: one 1024-thread block per session b =================
// Register budget by construction: threads 0..799 own (gate-row j, half h);
// weight cache = 13 float4 = 52 VGPR (reused for W_ih then W_hh). Partial
// dots combine via LDS. Peak live ~75 VGPR < 128 cap (131072/1024) -> no spill
// (R4/R5 held 200 VGPRs against a 128 cap and spilled ~12MB to scratch).
__global__ __launch_bounds__(1024,1) void prep_kernel(
    const int* __restrict__ seq, const int* __restrict__ ss2,
    const int* __restrict__ sn2, const int* __restrict__ mask,
    const float* __restrict__ user, const float* __restrict__ item,
    const float* __restrict__ W_ih, const float* __restrict__ W_hh,
    const float* __restrict__ b_ih, const float* __restrict__ b_hh,
    const float* __restrict__ W1, const float* __restrict__ W2,
    const float* __restrict__ Wg0,
    unsigned short* __restrict__ srb, unsigned short* __restrict__ ib){
  int b = blockIdx.x, tid = threadIdx.x;
  __shared__ float4 xsa[L_SEQ][25];     //  8,000 B
  __shared__ float  psum[L_SEQ][800];   // 64,000 B (x-part partials = gx)
  __shared__ float  ps2[800];           //  3,200 B (h-part partials, per step)
  __shared__ float  biasv[400];         //  1,600 B
  __shared__ float4 hs4[25];            //    400 B
  __shared__ float4 hu4[L_SEQ][25];     //  8,000 B
  __shared__ float4 stxs4[5][25];       //  2,000 B
  __shared__ float4 stcat4[5][50];      //  4,000 B
  __shared__ float  ls2l[5][100];       //  2,000 B
  __shared__ float  ns[6][100];         //  2,400 B
  __shared__ float  wsc[8];
  __shared__ float  ctx[100];
  __shared__ float4 h04[25];            float* h0l = (float*)h04;
  float* hs = (float*)hs4;

  const bool act = tid < 800;
  const int  half = (tid >= 400) ? 1 : 0;       // valid when act
  const int  j    = (tid < 400) ? tid : tid - 400;
  const int  kb   = half ? 13 : 0;              // float4 offset of this half

  // ---- stage: x rows, bias, h0 ----
  for (int idx = tid; idx < 500; idx += 1024){
    int tt = idx/25, k = idx - tt*25;
    xsa[tt][k] = *(const float4*)(item + (size_t)seq[b*L_SEQ+tt]*E_DIM + k*4);
  }
  if (tid < 400) biasv[tid] = b_ih[tid] + b_hh[tid];
  if (tid < 100) hs[tid] = 0.f;

  // ---- phase 1a: x-part partial dots (W_ih half cached: 52 VGPR) ----
  float4 w[13];
  if (act){
    const float4* wr = (const float4*)(W_ih + (size_t)j*E_DIM) + kb;
#pragma unroll
    for (int k=0;k<12;k++) w[k] = wr[k];
    w[12] = half ? (float4){0.f,0.f,0.f,0.f} : wr[12];
  }
  __syncthreads();
  if (act){
    for (int tt=0; tt<L_SEQ; tt++){
      float acc = 0.f;
#pragma unroll
      for (int k=0;k<12;k++) acc += dot4(w[k], xsa[tt][kb+k]);
      if (!half) acc += dot4(w[12], xsa[tt][12]);
      psum[tt][half*400 + j] = acc;
    }
    // swap weight cache to W_hh half (same registers, disjoint use)
    const float4* wr = (const float4*)(W_hh + (size_t)j*E_DIM) + kb;
#pragma unroll
    for (int k=0;k<12;k++) w[k] = wr[k];
    w[12] = half ? (float4){0.f,0.f,0.f,0.f} : wr[12];
  }

  // ---- phase 1b: recurrence ----
  float c = 0.f;
  __syncthreads();
  for (int tt=0; tt<L_SEQ; tt++){
    if (act){
      float acc = 0.f;
#pragma unroll
      for (int k=0;k<12;k++) acc += dot4(w[k], hs4[kb+k]);
      if (!half) acc += dot4(w[12], hs4[12]);
      ps2[half*400 + j] = acc;
    }
    __syncthreads();                   // partials ready; hs(t-1) reads done
    if (tid < 100){
      float g0 = psum[tt][tid    ] + psum[tt][tid+400] + ps2[tid    ] + ps2[tid+400] + biasv[tid    ];
      float g1 = psum[tt][tid+100] + psum[tt][tid+500] + ps2[tid+100] + ps2[tid+500] + biasv[tid+100];
      float g2 = psum[tt][tid+200] + psum[tt][tid+600] + ps2[tid+200] + ps2[tid+600] + biasv[tid+200];
      float g3 = psum[tt][tid+300] + psum[tt][tid+700] + ps2[tid+300] + ps2[tid+700] + biasv[tid+300];
      float ig=sigmoidf_(g0), fg=sigmoidf_(g1);
      float gg=tanhf(g2),     og=sigmoidf_(g3);
      c = fg*c + ig*gg;
      float h = og*tanhf(c);
      hs[tid] = h;
      ((float*)hu4[tt])[tid] = h;
    }
    __syncthreads();                   // hs(t) visible
  }

  // ---- phase 2: stageb for sessions n = 5b..5b+4 ----
  int s = tid / 100, j2 = tid - s*100;  // tid<500 active
  if (tid < 500){
    int n = b*5 + s;
    ((float*)stxs4)[s*100 + j2]  = item[(size_t)ss2[n*L_SEQ]*E_DIM + j2];
    ((float*)stcat4)[s*200 + j2] = user[(size_t)sn2[n]*E_DIM + j2];
  }
  __syncthreads();
  if (tid < 500){
    float ai=b_ih[j2]+b_hh[j2], ag=b_ih[200+j2]+b_hh[200+j2], ao=b_ih[300+j2]+b_hh[300+j2];
    const float4* wi=(const float4*)(W_ih + (size_t)j2*E_DIM);
    const float4* wg=(const float4*)(W_ih + (size_t)(200+j2)*E_DIM);
    const float4* wo=(const float4*)(W_ih + (size_t)(300+j2)*E_DIM);
#pragma unroll
    for (int k=0;k<25;k++){
      float4 x=stxs4[s][k];
      float4 a=wi[k]; ai += dot4(a,x);
      float4 g=wg[k]; ag += dot4(g,x);
      float4 o=wo[k]; ao += dot4(o,x);
    }
    float c0 = sigmoidf_(ai)*tanhf(ag);
    ((float*)stcat4)[s*200 + 100 + j2] = sigmoidf_(ao)*tanhf(c0);
  }
  __syncthreads();
  if (tid < 500){
    float acc = 0.f;
    const float4* w1=(const float4*)(W1 + (size_t)j2*200);
#pragma unroll
    for (int k=0;k<50;k++) acc += dot4(w1[k], stcat4[s][k]);
    ls2l[s][j2] = fmaxf(acc, 0.f);
  }
  __syncthreads();

  // ---- phase 3: GAT -> h0l ----
  if (tid < 100) ns[5][tid] = ((float*)hu4[0])[tid];
  if (tid < 500) ns[s][j2] = ls2l[s][j2];
  __syncthreads();
  if (tid < 6){ float sc=0.f; for (int e=0;e<100;e++) sc += ns[5][e]*ns[tid][e]; wsc[tid]=sc; }
  __syncthreads();
  if (tid == 0){
    float m=wsc[0]; for (int k=1;k<6;k++) m=fmaxf(m,wsc[k]);
    float sum=0.f;
    for (int k=0;k<6;k++){ float e_=expf(wsc[k]-m); wsc[k]=e_; sum+=e_; }
    float inv=1.f/sum;
    for (int k=0;k<6;k++) wsc[k]*=inv;
  }
  __syncthreads();
  if (tid < 100){ float cx=0.f; for (int k=0;k<6;k++) cx += wsc[k]*ns[k][tid]; ctx[tid]=cx; }
  __syncthreads();
  if (tid < 100){
    float acc=0.f;
    for (int e=0;e<100;e++) acc += ctx[e]*Wg0[e*E_DIM + tid];
    h0l[tid] = fmaxf(acc, 0.f);
  }
  __syncthreads();

  // ---- phase 4: sr rows m = 20b..20b+19 (mask folded), bf16, K-pad ----
  {
    int mi8 = tid >> 7;                 // 0..7
    int jj  = tid & 127;                // 0..127
#pragma unroll
    for (int r=0;r<3;r++){
      int mi = r*8 + mi8;
      if (mi < L_SEQ){
        int m = b*L_SEQ + mi;
        unsigned short val = 0;
        if (jj < 100){
          float acc = 0.f;
          const float4* w2=(const float4*)(W2 + (size_t)jj*200);
#pragma unroll
          for (int k=0;k<25;k++) acc += dot4(w2[k],    hu4[mi][k]);
#pragma unroll
          for (int k=0;k<25;k++) acc += dot4(w2[25+k], h04[k]);
          acc *= (float)mask[m];
          val = f2bf(acc);
        }
        srb[(size_t)m*KP + jj] = val;
      }
    }
    if (b < 48 && tid < 128) srb[(size_t)(MROWS + b)*KP + tid] = 0;
  }

  // ---- phase 5: itemb slice rows [b*301, b*301+301), float4/lane ----
  {
    int v0 = b*301;
    int cnt = (v0 + 301 <= NVP) ? 301 : (NVP - v0);
    for (int idx = tid; idx < cnt*32; idx += 1024){
      int v  = v0 + (idx >> 5);
      int k4 = (idx & 31) << 2;                 // 0,4,...,124
      float4 x = (float4){0.f,0.f,0.f,0.f};
      if (v < NV && k4 < 100) x = *(const float4*)(item + (size_t)v*E_DIM + k4);
      unsigned short p0=f2bf(x.x), p1=f2bf(x.y), p2=f2bf(x.z), p3=f2bf(x.w);
      unsigned int lo = (unsigned int)p0 | ((unsigned int)p1<<16);
      unsigned int hi = (unsigned int)p2 | ((unsigned int)p3<<16);
      unsigned int* dst = (unsigned int*)(ib + (size_t)v*KP + k4);
      dst[0] = lo; dst[1] = hi;
    }
  }
}

// ================= GEMM: logits = srb @ ib^T (bf16 MFMA, f32 acc) ========
// Operand-swapped (A-op = ib rows -> v on C/D row axis) => float4 stores.
// Swizzle: each XCD owns 2 m-panels, sweeps tile_n contiguously.
__global__ __launch_bounds__(256) void gemm_kernel(
    const unsigned short* __restrict__ srb, const unsigned short* __restrict__ ib,
    float* __restrict__ out){
  __shared__ unsigned short As[128*KP];
  __shared__ unsigned short Bs[128*KP];
  int orig = blockIdx.x;               // 0..3759 = 8 XCD * 470
  int xcd  = orig & 7;
  int p    = orig >> 3;                // sequential within an XCD
  int tile_n = p >> 1;                 // 0..234
  int tile_m = (xcd << 1) | (p & 1);   // 0..15
  int tid = threadIdx.x;
  const float4* Ag = (const float4*)(srb + (size_t)tile_m*128*KP);
  const float4* Bg = (const float4*)(ib  + (size_t)tile_n*128*KP);
  float4* As4=(float4*)As; float4* Bs4=(float4*)Bs;
#pragma unroll
  for (int i=0;i<8;i++){
    int chunk = i*256 + tid;
    int row = chunk >> 4;
    int cb  = (chunk & 15) << 4;
    int sw  = cb ^ ((row & 7) << 4);   // XOR swizzle (G4: D=128 bf16 rows)
    int di  = row*16 + (sw >> 4);
    As4[di] = Ag[chunk];
    Bs4[di] = Bg[chunk];
  }
  __syncthreads();
  int wave = tid >> 6, lane = tid & 63;
  int wm = (wave >> 1) << 6, wn = (wave & 1) << 6;
  int lrow = lane & 15, lq = lane >> 4;
  f32x4 acc[4][4];
#pragma unroll
  for (int i=0;i<4;i++)
#pragma unroll
    for (int jj=0;jj<4;jj++) acc[i][jj] = (f32x4){0.f,0.f,0.f,0.f};
#pragma unroll
  for (int kk=0;kk<4;kk++){
    int koffb = (kk*32 + lq*8) * 2;
    bf16x8 a[4], bfr[4];
#pragma unroll
    for (int i=0;i<4;i++){
      int row = wm + i*16 + lrow;
      int boff = koffb ^ ((row & 7) << 4);
      a[i] = *(const bf16x8*)(As + row*KP + (boff >> 1));
    }
#pragma unroll
    for (int jj=0;jj<4;jj++){
      int row = wn + jj*16 + lrow;
      int boff = koffb ^ ((row & 7) << 4);
      bfr[jj] = *(const bf16x8*)(Bs + row*KP + (boff >> 1));
    }
#pragma unroll
    for (int i=0;i<4;i++)
#pragma unroll
      for (int jj=0;jj<4;jj++)
        acc[i][jj] = __builtin_amdgcn_mfma_f32_16x16x32_bf16(bfr[jj], a[i], acc[i][jj], 0, 0, 0);
  }
  // C/D col(lane&15) = srb row (m); C/D row((lane>>4)*4+r) = ib row (v)
  int v0 = tile_n*128 + wn + lq*4;
  int m0 = tile_m*128 + wm + lrow;
#pragma unroll
  for (int i=0;i<4;i++){
    int m = m0 + i*16;
    if (m < MROWS){
#pragma unroll
      for (int jj=0;jj<4;jj++){
        int v = v0 + jj*16;
        if (v < NV)
          *(float4*)(out + (size_t)m*NV + v) = (float4){acc[i][jj][0], acc[i][jj][1], acc[i][jj][2], acc[i][jj][3]};
      }
    }
  }
}

extern "C" void kernel_launch(void* const* d_in, const int* in_sizes, int n_in,
                              void* d_out, int out_size, void* d_ws, size_t ws_size,
                              hipStream_t stream) {
  const int*   seq  = (const int*)d_in[0];
  const int*   sn2  = (const int*)d_in[2];
  const int*   ss2  = (const int*)d_in[4];
  const int*   mask = (const int*)d_in[5];
  const float* user = (const float*)d_in[6];
  const float* item = (const float*)d_in[7];
  const float* W_ih = (const float*)d_in[8];
  const float* W_hh = (const float*)d_in[9];
  const float* b_ih = (const float*)d_in[10];
  const float* b_hh = (const float*)d_in[11];
  const float* W1   = (const float*)d_in[12];
  const float* W2   = (const float*)d_in[13];
  const float* Wg0  = (const float*)d_in[14];
  float* out = (float*)d_out;
  char* ws = (char*)d_ws;

  unsigned short* srb = (unsigned short*)(ws);            // 2048*128*2 = 524,288 B
  unsigned short* ib  = (unsigned short*)(ws + 1048576);  // 30080*128*2 = 7,700,480 B

  prep_kernel<<<dim3(100), dim3(1024), 0, stream>>>(
      seq, ss2, sn2, mask, user, item, W_ih, W_hh, b_ih, b_hh, W1, W2, Wg0, srb, ib);
  gemm_kernel<<<dim3(3760), dim3(256), 0, stream>>>(srb, ib, out);
}

// Round 7
// 141.414 us; speedup vs baseline: 1.2771x; 1.2771x over previous
//
#include <hip/hip_runtime.h>

typedef __attribute__((ext_vector_type(8))) short bf16x8;
typedef __attribute__((ext_vector_type(4))) float f32x4;
typedef __attribute__((ext_vector_type(4))) unsigned short us4;

#define E_DIM 100
#define L_SEQ 20
#define NV    30000
#define NVP   30080
#define MROWS 2000
#define KP    128
#define MR2   2560      // xg rows: 0..1999 session-steps, 2048..2547 support first-tokens
#define NW    512       // padded gate rows
#define KW    112       // whh padded K

__device__ inline float sigmoidf_(float x){ return 1.f/(1.f+expf(-x)); }
__device__ inline unsigned short f2bf(float f){
  unsigned int u = __float_as_uint(f);
  return (unsigned short)((u + 0x7fffu + ((u>>16)&1u)) >> 16);
}
__device__ inline float dot4(float4 a, float4 b){
  return a.x*b.x + a.y*b.y + a.z*b.z + a.w*b.w;
}
__device__ inline void store4bf(unsigned short* dst, float4 x){
  us4 p = { f2bf(x.x), f2bf(x.y), f2bf(x.z), f2bf(x.w) };
  *(us4*)dst = p;
}

// ---------------- G: build all bf16 operands (pure streaming) ----------------
// regions: ib[30080][128], xg[2560][128], wihb[512][128], whhb[400][112], biasv[512]
#define N_IB   962560
#define C1     962560
#define C2    1044480
#define C3    1060864
#define C4    1072064
#define C5    1072576
__global__ void gather_kernel(const int* __restrict__ seq, const int* __restrict__ ss2,
    const float* __restrict__ item, const float* __restrict__ W_ih,
    const float* __restrict__ W_hh, const float* __restrict__ b_ih,
    const float* __restrict__ b_hh,
    unsigned short* __restrict__ ib, unsigned short* __restrict__ xg,
    unsigned short* __restrict__ wihb, unsigned short* __restrict__ whhb,
    float* __restrict__ biasv){
  int id = blockIdx.x*256 + threadIdx.x;
  if (id < C1){
    int v = id >> 5, k4 = (id & 31) << 2;
    float4 x = {0.f,0.f,0.f,0.f};
    if (v < NV && k4 < 100) x = *(const float4*)(item + (size_t)v*E_DIM + k4);
    store4bf(ib + (size_t)v*KP + k4, x);
  } else if (id < C2){
    int idx = id - C1;
    int m = idx >> 5, k4 = (idx & 31) << 2;
    int src = -1;
    if (m < MROWS) src = seq[m];
    else if (m >= 2048 && m < 2548) src = ss2[(m-2048)*L_SEQ];
    float4 x = {0.f,0.f,0.f,0.f};
    if (src >= 0 && k4 < 100) x = *(const float4*)(item + (size_t)src*E_DIM + k4);
    store4bf(xg + (size_t)m*KP + k4, x);
  } else if (id < C3){
    int idx = id - C2;
    int j = idx >> 5, k4 = (idx & 31) << 2;
    float4 x = {0.f,0.f,0.f,0.f};
    if (j < 400 && k4 < 100) x = *(const float4*)(W_ih + (size_t)j*E_DIM + k4);
    store4bf(wihb + (size_t)j*KP + k4, x);
  } else if (id < C4){
    int idx = id - C3;
    int j = idx / 28, k4 = (idx - j*28) << 2;
    float4 x = {0.f,0.f,0.f,0.f};
    if (k4 < 100) x = *(const float4*)(W_hh + (size_t)j*E_DIM + k4);
    store4bf(whhb + (size_t)j*KW + k4, x);
  } else if (id < C5){
    int n = id - C4;
    biasv[n] = (n < 400) ? (b_ih[n] + b_hh[n]) : 0.f;
  }
}

// ---------------- GX: gx[m][n] = xg[m] . wihb[n] + biasv[n] (MFMA) ----------------
// Same structure as the verified logits GEMM; A-op = wihb rows (n on C/D row axis).
__global__ __launch_bounds__(256) void gxgemm_kernel(
    const unsigned short* __restrict__ xg, const unsigned short* __restrict__ wihb,
    const float* __restrict__ biasv, float* __restrict__ gx){
  __shared__ unsigned short As[128*KP];
  __shared__ unsigned short Bs[128*KP];
  int tile_m = blockIdx.x >> 2;        // 0..19
  int tile_n = blockIdx.x & 3;         // 0..3
  int tid = threadIdx.x;
  const float4* Ag = (const float4*)(xg   + (size_t)tile_m*128*KP);
  const float4* Bg = (const float4*)(wihb + (size_t)tile_n*128*KP);
  float4* As4=(float4*)As; float4* Bs4=(float4*)Bs;
#pragma unroll
  for (int i=0;i<8;i++){
    int chunk = i*256 + tid;
    int row = chunk >> 4;
    int cb  = (chunk & 15) << 4;
    int sw  = cb ^ ((row & 7) << 4);
    int di  = row*16 + (sw >> 4);
    As4[di] = Ag[chunk];
    Bs4[di] = Bg[chunk];
  }
  __syncthreads();
  int wave = tid >> 6, lane = tid & 63;
  int wm = (wave >> 1) << 6, wn = (wave & 1) << 6;
  int lrow = lane & 15, lq = lane >> 4;
  f32x4 acc[4][4];
#pragma unroll
  for (int i=0;i<4;i++)
#pragma unroll
    for (int jj=0;jj<4;jj++) acc[i][jj] = (f32x4){0.f,0.f,0.f,0.f};
#pragma unroll
  for (int kk=0;kk<4;kk++){
    int koffb = (kk*32 + lq*8) * 2;
    bf16x8 a[4], bfr[4];
#pragma unroll
    for (int i=0;i<4;i++){
      int row = wm + i*16 + lrow;
      int boff = koffb ^ ((row & 7) << 4);
      a[i] = *(const bf16x8*)(As + row*KP + (boff >> 1));
    }
#pragma unroll
    for (int jj=0;jj<4;jj++){
      int row = wn + jj*16 + lrow;
      int boff = koffb ^ ((row & 7) << 4);
      bfr[jj] = *(const bf16x8*)(Bs + row*KP + (boff >> 1));
    }
#pragma unroll
    for (int i=0;i<4;i++)
#pragma unroll
      for (int jj=0;jj<4;jj++)
        acc[i][jj] = __builtin_amdgcn_mfma_f32_16x16x32_bf16(bfr[jj], a[i], acc[i][jj], 0, 0, 0);
  }
  // C/D col = xg row (m); C/D row-axis = wihb row (n)
  int n0 = tile_n*128 + wn + lq*4;
  int m0 = tile_m*128 + wm + lrow;
#pragma unroll
  for (int i=0;i<4;i++){
    int m = m0 + i*16;
#pragma unroll
    for (int jj=0;jj<4;jj++){
      int n = n0 + jj*16;
      if (n < 400){
        float4 bv = *(const float4*)(biasv + n);
        *(float4*)(gx + (size_t)m*400 + n) =
          (float4){acc[i][jj][0]+bv.x, acc[i][jj][1]+bv.y, acc[i][jj][2]+bv.z, acc[i][jj][3]+bv.w};
      }
    }
  }
}

// ---------------- PREP: one 512-thread block per session b ----------------
// Recurrence reads W_hh bf16 from LDS (XOR-swizzled b128), h stays f32.
// No per-thread weight arrays anywhere -> ~15 live VGPRs, no spill possible.
__global__ __launch_bounds__(512,1) void prep_kernel(
    const int* __restrict__ sn2, const int* __restrict__ mask,
    const float* __restrict__ user, const float* __restrict__ W1,
    const float* __restrict__ W2, const float* __restrict__ Wg0,
    const unsigned short* __restrict__ whhb, const float* __restrict__ gx,
    unsigned short* __restrict__ srb){
  int b = blockIdx.x, tid = threadIdx.x;
  __shared__ unsigned char Wsh[400*KW*2];   // 89,600 B swizzled bf16
  __shared__ float  hsf[KW];                // h, f32, zero-padded
  __shared__ float  gsh[400];
  __shared__ float4 hu4[L_SEQ][25];
  __shared__ float4 stcat4[5][50];
  __shared__ float  ls2l[5][100];
  __shared__ float  ns[6][100];
  __shared__ float  wsc[8];
  __shared__ float  ctx[100];
  __shared__ float4 h04[25];

  // stage W_hh (5600 16B units) with XOR swizzle
  for (int u = tid; u < 5600; u += 512){
    int j = u / 14;
    int byte = (u*16) ^ ((j & 7) << 4);
    *(int4*)(Wsh + byte) = *(const int4*)((const char*)whhb + (size_t)u*16);
  }
  if (tid < KW) hsf[tid] = 0.f;
  __syncthreads();

  // ---- phase 1: recurrence (x-part + bias preloaded in gx) ----
  float c = 0.f;
  for (int tt=0; tt<L_SEQ; tt++){
    if (tid < 400){
      float acc = gx[((size_t)b*L_SEQ + tt)*400 + tid];
      const float4* h4 = (const float4*)hsf;
#pragma unroll
      for (int q=0;q<14;q++){
        int4 wd = *(const int4*)(Wsh + (((tid*14+q)*16) ^ ((tid&7)<<4)));
        float4 ha = h4[q*2], hb = h4[q*2+1];
        acc += __uint_as_float(((unsigned)wd.x)<<16)        *ha.x
             + __uint_as_float(((unsigned)wd.x)&0xFFFF0000u)*ha.y
             + __uint_as_float(((unsigned)wd.y)<<16)        *ha.z
             + __uint_as_float(((unsigned)wd.y)&0xFFFF0000u)*ha.w
             + __uint_as_float(((unsigned)wd.z)<<16)        *hb.x
             + __uint_as_float(((unsigned)wd.z)&0xFFFF0000u)*hb.y
             + __uint_as_float(((unsigned)wd.w)<<16)        *hb.z
             + __uint_as_float(((unsigned)wd.w)&0xFFFF0000u)*hb.w;
      }
      gsh[tid] = acc;
    }
    __syncthreads();
    if (tid < 100){
      float ig=sigmoidf_(gsh[tid]), fg=sigmoidf_(gsh[tid+100]);
      float gg=tanhf(gsh[tid+200]), og=sigmoidf_(gsh[tid+300]);
      c = fg*c + ig*gg;
      float h = og*tanhf(c);
      hsf[tid] = h;
      ((float*)hu4[tt])[tid] = h;
    }
    __syncthreads();
  }

  // ---- phase 2: stageb (x-gates from gx rows 2048+n) ----
  int s = tid / 100, j2 = tid - s*100;
  if (tid < 500){
    int n = b*5 + s;
    ((float*)stcat4)[s*200 + j2] = user[(size_t)sn2[n]*E_DIM + j2];
    const float* gr = gx + (size_t)(2048+n)*400;
    float c0  = sigmoidf_(gr[j2]) * tanhf(gr[200+j2]);
    ((float*)stcat4)[s*200 + 100 + j2] = sigmoidf_(gr[300+j2]) * tanhf(c0);
  }
  __syncthreads();
  if (tid < 500){
    float acc = 0.f;
    const float4* w1=(const float4*)(W1 + (size_t)j2*200);
#pragma unroll
    for (int k=0;k<50;k++) acc += dot4(w1[k], stcat4[s][k]);
    ls2l[s][j2] = fmaxf(acc, 0.f);
  }
  __syncthreads();

  // ---- phase 3: GAT -> h04 ----
  if (tid < 100) ns[5][tid] = ((float*)hu4[0])[tid];
  if (tid < 500) ns[s][j2] = ls2l[s][j2];
  __syncthreads();
  if (tid < 6){ float sc=0.f; for (int e=0;e<100;e++) sc += ns[5][e]*ns[tid][e]; wsc[tid]=sc; }
  __syncthreads();
  if (tid == 0){
    float m=wsc[0]; for (int k=1;k<6;k++) m=fmaxf(m,wsc[k]);
    float sum=0.f;
    for (int k=0;k<6;k++){ float e_=expf(wsc[k]-m); wsc[k]=e_; sum+=e_; }
    float inv=1.f/sum;
    for (int k=0;k<6;k++) wsc[k]*=inv;
  }
  __syncthreads();
  if (tid < 100){ float cx=0.f; for (int k=0;k<6;k++) cx += wsc[k]*ns[k][tid]; ctx[tid]=cx; }
  __syncthreads();
  if (tid < 100){
    float acc=0.f;
    for (int e=0;e<100;e++) acc += ctx[e]*Wg0[e*E_DIM + tid];
    ((float*)h04)[tid] = fmaxf(acc, 0.f);
  }
  __syncthreads();

  // ---- phase 4: sr rows (mask folded), bf16, K-pad ----
  {
    int mi4 = tid >> 7;                 // 0..3
    int jj  = tid & 127;
#pragma unroll
    for (int r=0;r<5;r++){
      int mi = r*4 + mi4;
      int m  = b*L_SEQ + mi;
      unsigned short val = 0;
      if (jj < 100){
        float acc = 0.f;
        const float4* w2=(const float4*)(W2 + (size_t)jj*200);
#pragma unroll
        for (int k=0;k<25;k++) acc += dot4(w2[k],    hu4[mi][k]);
#pragma unroll
        for (int k=0;k<25;k++) acc += dot4(w2[25+k], h04[k]);
        acc *= (float)mask[m];
        val = f2bf(acc);
      }
      srb[(size_t)m*KP + jj] = val;
    }
    if (b < 48 && tid < 128) srb[(size_t)(MROWS + b)*KP + tid] = 0;
  }
}

// ---------------- E: logits = srb @ ib^T (bf16 MFMA, f32 acc) ----------------
__global__ __launch_bounds__(256) void gemm_kernel(
    const unsigned short* __restrict__ srb, const unsigned short* __restrict__ ib,
    float* __restrict__ out){
  __shared__ unsigned short As[128*KP];
  __shared__ unsigned short Bs[128*KP];
  int orig = blockIdx.x;               // 0..3759 = 8 XCD * 470
  int xcd  = orig & 7;
  int p    = orig >> 3;
  int tile_n = p >> 1;
  int tile_m = (xcd << 1) | (p & 1);
  int tid = threadIdx.x;
  const float4* Ag = (const float4*)(srb + (size_t)tile_m*128*KP);
  const float4* Bg = (const float4*)(ib  + (size_t)tile_n*128*KP);
  float4* As4=(float4*)As; float4* Bs4=(float4*)Bs;
#pragma unroll
  for (int i=0;i<8;i++){
    int chunk = i*256 + tid;
    int row = chunk >> 4;
    int cb  = (chunk & 15) << 4;
    int sw  = cb ^ ((row & 7) << 4);
    int di  = row*16 + (sw >> 4);
    As4[di] = Ag[chunk];
    Bs4[di] = Bg[chunk];
  }
  __syncthreads();
  int wave = tid >> 6, lane = tid & 63;
  int wm = (wave >> 1) << 6, wn = (wave & 1) << 6;
  int lrow = lane & 15, lq = lane >> 4;
  f32x4 acc[4][4];
#pragma unroll
  for (int i=0;i<4;i++)
#pragma unroll
    for (int jj=0;jj<4;jj++) acc[i][jj] = (f32x4){0.f,0.f,0.f,0.f};
#pragma unroll
  for (int kk=0;kk<4;kk++){
    int koffb = (kk*32 + lq*8) * 2;
    bf16x8 a[4], bfr[4];
#pragma unroll
    for (int i=0;i<4;i++){
      int row = wm + i*16 + lrow;
      int boff = koffb ^ ((row & 7) << 4);
      a[i] = *(const bf16x8*)(As + row*KP + (boff >> 1));
    }
#pragma unroll
    for (int jj=0;jj<4;jj++){
      int row = wn + jj*16 + lrow;
      int boff = koffb ^ ((row & 7) << 4);
      bfr[jj] = *(const bf16x8*)(Bs + row*KP + (boff >> 1));
    }
#pragma unroll
    for (int i=0;i<4;i++)
#pragma unroll
      for (int jj=0;jj<4;jj++)
        acc[i][jj] = __builtin_amdgcn_mfma_f32_16x16x32_bf16(bfr[jj], a[i], acc[i][jj], 0, 0, 0);
  }
  int v0 = tile_n*128 + wn + lq*4;
  int m0 = tile_m*128 + wm + lrow;
#pragma unroll
  for (int i=0;i<4;i++){
    int m = m0 + i*16;
    if (m < MROWS){
#pragma unroll
      for (int jj=0;jj<4;jj++){
        int v = v0 + jj*16;
        if (v < NV)
          *(float4*)(out + (size_t)m*NV + v) = (float4){acc[i][jj][0], acc[i][jj][1], acc[i][jj][2], acc[i][jj][3]};
      }
    }
  }
}

extern "C" void kernel_launch(void* const* d_in, const int* in_sizes, int n_in,
                              void* d_out, int out_size, void* d_ws, size_t ws_size,
                              hipStream_t stream) {
  const int*   seq  = (const int*)d_in[0];
  const int*   sn2  = (const int*)d_in[2];
  const int*   ss2  = (const int*)d_in[4];
  const int*   mask = (const int*)d_in[5];
  const float* user = (const float*)d_in[6];
  const float* item = (const float*)d_in[7];
  const float* W_ih = (const float*)d_in[8];
  const float* W_hh = (const float*)d_in[9];
  const float* b_ih = (const float*)d_in[10];
  const float* b_hh = (const float*)d_in[11];
  const float* W1   = (const float*)d_in[12];
  const float* W2   = (const float*)d_in[13];
  const float* Wg0  = (const float*)d_in[14];
  float* out = (float*)d_out;
  char* ws = (char*)d_ws;

  unsigned short* ib    = (unsigned short*)(ws);              // 7,700,480 B
  unsigned short* srb   = (unsigned short*)(ws + 7700480);    //   524,288 B
  unsigned short* xg    = (unsigned short*)(ws + 8224768);    //   655,360 B
  unsigned short* wihb  = (unsigned short*)(ws + 8880128);    //   131,072 B
  unsigned short* whhb  = (unsigned short*)(ws + 9011200);    //    89,600 B
  float*          biasv = (float*)(ws + 9100800);             //     2,048 B
  float*          gx    = (float*)(ws + 9102848);             // 4,096,000 B

  gather_kernel<<<dim3(4190), dim3(256), 0, stream>>>(
      seq, ss2, item, W_ih, W_hh, b_ih, b_hh, ib, xg, wihb, whhb, biasv);
  gxgemm_kernel<<<dim3(80), dim3(256), 0, stream>>>(xg, wihb, biasv, gx);
  prep_kernel<<<dim3(100), dim3(512), 0, stream>>>(
      sn2, mask, user, W1, W2, Wg0, whhb, gx, srb);
  gemm_kernel<<<dim3(3760), dim3(256), 0, stream>>>(srb, ib, out);
}